// Round 6
// baseline (225.488 us; speedup 1.0000x reference)
//
#include <hip/hip_runtime.h>
#include <math.h>

#define BATCH 128
#define LN_EPS 1e-5f

typedef short bf16x8 __attribute__((ext_vector_type(8)));
typedef short bf16x4 __attribute__((ext_vector_type(4)));
typedef float f32x4  __attribute__((ext_vector_type(4)));

__device__ __forceinline__ ushort f2bf(float f) {
    union { float f; unsigned u; } c; c.f = f;
    unsigned r = c.u + 0x7FFF + ((c.u >> 16) & 1);   // round-nearest-even
    return (ushort)(r >> 16);
}

__device__ __forceinline__ float fast_tanh(float v) {
    float e = __expf(2.f * v);
    return 1.f - 2.f / (e + 1.f);
}

// ---------------------------------------------------------------------------
// prep:
//  idx < 32768: Wm23 = bf16 A-frag (tap-split layout) for cw2 (s=0), cw3 (s=1)
//  idx < 64   : per-ch composite of token-conv with conv1:
//      Weff[ch][j<12]  -> Wm1 bf16 A-frag (16x16x32, taps >=12 zero)
//      cbt[kk][ch]     = sum_din cw1[ch][din][kk] * token_bias[din]
//      W0c[ch][u<4]    = sum_din cw1[ch][din][0] * w9p[din][5+u]   (l=0 fix)
//      W3c[ch][u<4]    = sum_din cw1[ch][din][3] * w9p[din][u]     (l=2047 fix)
// ---------------------------------------------------------------------------
__global__ void prep_kernel(const float* __restrict__ cw1, const float* __restrict__ cw2,
                            const float* __restrict__ cw3,
                            const float* __restrict__ w3, const float* __restrict__ b3,
                            const float* __restrict__ w5, const float* __restrict__ b5,
                            const float* __restrict__ w7, const float* __restrict__ b7,
                            const float* __restrict__ w9, const float* __restrict__ b9,
                            ushort* __restrict__ Wm23, ushort* __restrict__ Wm1,
                            float* __restrict__ cbt, float* __restrict__ W0c,
                            float* __restrict__ W3c) {
    int idx = blockIdx.x * 256 + threadIdx.x;      // grid covers 2*16384
    if (idx < 2 * 16384) {
        int s = idx >> 14, r = idx & 16383;
        int j = r & 7, l15 = (r >> 3) & 15, dt = (r >> 7) & 3;
        int quad = (r >> 9) & 3, k2 = (r >> 11) & 1, kk = (r >> 12) & 3;
        int dout = dt * 16 + l15, din = k2 * 32 + quad * 8 + j;
        const float* cw = (s == 0) ? cw2 : cw3;
        Wm23[idx] = f2bf(cw[dout * 256 + din * 4 + kk]);
    }
    if (idx < 64) {
        const int ch = idx;
        const float* cw1row = cw1 + ch * 256;
        float weff[12], cbtv[4], w0c[4], w3c[4];
#pragma unroll
        for (int j = 0; j < 12; ++j) weff[j] = 0.f;
#pragma unroll
        for (int k = 0; k < 4; ++k) { cbtv[k] = 0.f; w0c[k] = 0.f; w3c[k] = 0.f; }
        for (int din = 0; din < 64; ++din) {
            int ki = din & 3, g = din >> 2;
            float wl[9];
#pragma unroll
            for (int j = 0; j < 9; ++j) wl[j] = 0.f;
            float bias;
            if (ki == 0)      { for (int j = 0; j < 3; ++j) wl[3 + j] = w3[g * 3 + j]; bias = b3[g]; }
            else if (ki == 1) { for (int j = 0; j < 5; ++j) wl[2 + j] = w5[g * 5 + j]; bias = b5[g]; }
            else if (ki == 2) { for (int j = 0; j < 7; ++j) wl[1 + j] = w7[g * 7 + j]; bias = b7[g]; }
            else              { for (int j = 0; j < 9; ++j) wl[j]     = w9[g * 9 + j]; bias = b9[g]; }
#pragma unroll
            for (int kk = 0; kk < 4; ++kk) {
                float c = cw1row[din * 4 + kk];
                cbtv[kk] += c * bias;
#pragma unroll
                for (int u = 0; u < 9; ++u) weff[kk + u] += c * wl[u];
            }
            float c0 = cw1row[din * 4 + 0], c3 = cw1row[din * 4 + 3];
#pragma unroll
            for (int u = 0; u < 4; ++u) { w0c[u] += c0 * wl[5 + u]; w3c[u] += c3 * wl[u]; }
        }
        int dt = ch >> 4, l15 = ch & 15;
#pragma unroll
        for (int quad = 0; quad < 4; ++quad)
#pragma unroll
            for (int j = 0; j < 8; ++j) {
                int k = quad * 8 + j;
                Wm1[((quad * 4 + dt) * 16 + l15) * 8 + j] = f2bf(k < 12 ? weff[k] : 0.f);
            }
#pragma unroll
        for (int kk = 0; kk < 4; ++kk) cbt[kk * 64 + ch] = cbtv[kk];
#pragma unroll
        for (int u = 0; u < 4; ++u) { W0c[ch * 4 + u] = w0c[u]; W3c[ch * 4 + u] = w3c[u]; }
    }
}

// ---------------------------------------------------------------------------
// pe1c[l][ch] = cb1[ch] + conv1(pe)[ch][l] + sum_{kk valid at l} cbt[kk][ch]
// (fp32, batch-independent; kk=0 invalid at l=0, kk=3 invalid at l=2047)
// ---------------------------------------------------------------------------
__global__ __launch_bounds__(256, 2)
void pe1_kernel(const float* __restrict__ cw1, const float* __restrict__ cb1,
                const float* __restrict__ cbt, float* __restrict__ pe1c) {
    __shared__ float tile[64][132];
    const int tid = threadIdx.x;
    const int l0 = blockIdx.x * 64;
    const int pin0 = 2 * l0 - 1;
    for (int idx = tid; idx < 64 * 130; idx += 256) {
        int d = idx / 130, pp = idx - d * 130;
        int p = pin0 + pp;
        float v = 0.f;
        if (p >= 0 && p < 4096) {
            float dv = __expf((float)(d & ~1) * -0.14391156831212787f);  // -ln(1e4)/64
            float ang = (float)p * dv;
            v = (d & 1) ? __cosf(ang) : __sinf(ang);
        }
        tile[d][pp] = v;
    }
    __syncthreads();
    const int lane = tid & 63, wv = tid >> 6;
    const int l = l0 + lane, db = wv * 16;
    float acc[16];
#pragma unroll
    for (int j = 0; j < 16; ++j) {
        int ch = db + j;
        float a = cb1[ch] + cbt[64 + ch] + cbt[128 + ch];
        if (l > 0) a += cbt[ch];
        if (l < 2047) a += cbt[192 + ch];
        acc[j] = a;
    }
    for (int din = 0; din < 64; ++din) {
        float v0 = tile[din][2 * lane + 0], v1 = tile[din][2 * lane + 1];
        float v2 = tile[din][2 * lane + 2], v3 = tile[din][2 * lane + 3];
        const float* wb = cw1 + din * 4;
#pragma unroll
        for (int j = 0; j < 16; ++j) {
            const float* wj = wb + (db + j) * 256;
            acc[j] = fmaf(v0, wj[0], fmaf(v1, wj[1], fmaf(v2, wj[2], fmaf(v3, wj[3], acc[j]))));
        }
    }
#pragma unroll
    for (int j = 0; j < 16; ++j) pe1c[(size_t)l * 64 + db + j] = acc[j];
}

// ---------------------------------------------------------------------------
// Stage 1 (composite 12-tap, stride-2 conv x -> 64ch via MFMA K=16):
// B-frag read straight from 1-D bf16 x-window: k=quad*8+j -> xbf[2m+8q+j].
// Epilogue: +pe1c (all biases folded), edge fix at l=0/2047, tanh, LN,
// pack bf16 -> h1 (B,2048,64) via LDS for coalesced stores.
// ---------------------------------------------------------------------------
__global__ __launch_bounds__(256, 4)
void stage1_mfma(const float* __restrict__ x, const ushort* __restrict__ Wm1,
                 const float* __restrict__ pe1c,
                 const float* __restrict__ W0c, const float* __restrict__ W3c,
                 const float* __restrict__ lng, const float* __restrict__ lnb,
                 ushort* __restrict__ hout) {
    const int b = blockIdx.y;
    const int l0 = blockIdx.x * 128;
    const int tid = threadIdx.x;

    __shared__ __align__(16) ushort xbf[304];
    __shared__ __align__(16) ushort OutT[128 * 72];

    for (int i = tid; i < 304; i += 256) {
        int g = 2 * l0 - 5 + i;
        float v = (i < 268 && g >= 0 && g < 4096) ? x[b * 4096 + g] : 0.f;
        xbf[i] = f2bf(v);
    }
    __syncthreads();

    const int wv = tid >> 6, lane = tid & 63;
    const int quad = lane >> 4, l15 = lane & 15;
    const int m0 = wv * 32;

    bf16x8 afr[4];
#pragma unroll
    for (int dt = 0; dt < 4; ++dt)
        afr[dt] = *(const bf16x8*)&Wm1[((quad * 4 + dt) * 16 + l15) * 8];

    f32x4 acc[2][4];
#pragma unroll
    for (int pt = 0; pt < 2; ++pt)
#pragma unroll
        for (int dt = 0; dt < 4; ++dt) acc[pt][dt] = (f32x4)0.f;

#pragma unroll
    for (int pt = 0; pt < 2; ++pt) {
        const int m = m0 + pt * 16 + l15;
        union { bf16x8 v; unsigned u[4]; } tmp;
        const unsigned* p = (const unsigned*)&xbf[2 * m + 8 * quad];  // 4B-aligned
#pragma unroll
        for (int i = 0; i < 4; ++i) tmp.u[i] = p[i];
#pragma unroll
        for (int dt = 0; dt < 4; ++dt)
            acc[pt][dt] = __builtin_amdgcn_mfma_f32_16x16x32_bf16(
                afr[dt], tmp.v, acc[pt][dt], 0, 0, 0);
    }

    float vln[2][16];
#pragma unroll
    for (int pt = 0; pt < 2; ++pt) {
        const int l = l0 + m0 + pt * 16 + l15;
        float v[16];
        const float* pb = pe1c + (size_t)l * 64;
#pragma unroll
        for (int dt = 0; dt < 4; ++dt) {
            float4 pv = *(const float4*)(pb + dt * 16 + quad * 4);
            v[dt * 4 + 0] = acc[pt][dt][0] + pv.x;
            v[dt * 4 + 1] = acc[pt][dt][1] + pv.y;
            v[dt * 4 + 2] = acc[pt][dt][2] + pv.z;
            v[dt * 4 + 3] = acc[pt][dt][3] + pv.w;
        }
        if (l == 0 || l == 2047) {   // conv1 zero-pads emb, not composite-x
            const float* Wc = (l == 0) ? W0c : W3c;
            const float* xe = x + b * 4096 + ((l == 0) ? 0 : 4092);
            float x0 = xe[0], x1 = xe[1], x2 = xe[2], x3 = xe[3];
#pragma unroll
            for (int dt = 0; dt < 4; ++dt)
#pragma unroll
                for (int r = 0; r < 4; ++r) {
                    int ch = dt * 16 + quad * 4 + r;
                    const float* wc = Wc + ch * 4;
                    v[dt * 4 + r] -= wc[0] * x0 + wc[1] * x1 + wc[2] * x2 + wc[3] * x3;
                }
        }
#pragma unroll
        for (int i = 0; i < 16; ++i) v[i] = fast_tanh(v[i]);
        float s = 0.f;
#pragma unroll
        for (int i = 0; i < 16; ++i) s += v[i];
        s += __shfl_xor(s, 16, 64);
        s += __shfl_xor(s, 32, 64);
        float mean = s * 0.015625f;
        float q = 0.f;
#pragma unroll
        for (int i = 0; i < 16; ++i) { float d = v[i] - mean; q = fmaf(d, d, q); }
        q += __shfl_xor(q, 16, 64);
        q += __shfl_xor(q, 32, 64);
        float rstd = rsqrtf(q * 0.015625f + LN_EPS);
#pragma unroll
        for (int dt = 0; dt < 4; ++dt)
#pragma unroll
            for (int r = 0; r < 4; ++r) {
                int ch = dt * 16 + quad * 4 + r;
                vln[pt][dt * 4 + r] = (v[dt * 4 + r] - mean) * rstd * lng[ch] + lnb[ch];
            }
    }
#pragma unroll
    for (int pt = 0; pt < 2; ++pt) {
        const int m = m0 + pt * 16 + l15;
#pragma unroll
        for (int dt = 0; dt < 4; ++dt) {
            bf16x4 pk;
            pk[0] = (short)f2bf(vln[pt][dt * 4 + 0]);
            pk[1] = (short)f2bf(vln[pt][dt * 4 + 1]);
            pk[2] = (short)f2bf(vln[pt][dt * 4 + 2]);
            pk[3] = (short)f2bf(vln[pt][dt * 4 + 3]);
            *(bf16x4*)&OutT[m * 72 + dt * 16 + quad * 4] = pk;
        }
    }
    __syncthreads();
    for (int idx = tid; idx < 1024; idx += 256) {
        int row = idx >> 3, chb = (idx & 7) * 8;
        *(bf16x8*)(hout + ((size_t)b * 2048 + l0 + row) * 64 + chb) =
            *(const bf16x8*)&OutT[row * 72 + chb];
    }
}

// ---------------------------------------------------------------------------
// Stages 2/3: tap-split MFMA conv(k=4,s=2,p=1), input (B,LIN,64) bf16.
// STAGE==2: tanh+LN -> bf16 (B,LOUT,64).  STAGE==3: tanh -> fp32 (B,512,64).
// ---------------------------------------------------------------------------
template <int STAGE>
__global__ __launch_bounds__(256, 4)
void stage_mfma(const ushort* __restrict__ hin, const ushort* __restrict__ Wg,
                const float* __restrict__ cb,
                const float* __restrict__ lng, const float* __restrict__ lnb,
                ushort* __restrict__ hout, float* __restrict__ out) {
    constexpr int LIN  = (STAGE == 2) ? 2048 : 1024;
    constexpr int LOUT = LIN / 2;
    const int b = blockIdx.y;
    const int l0 = blockIdx.x * 128;
    const int tid = threadIdx.x;

    __shared__ __align__(16) ushort TE[129][72];
    __shared__ __align__(16) ushort TO[129][72];

    for (int idx = tid; idx < 258 * 8; idx += 256) {
        int row = idx >> 3, chb = (idx & 7) * 8;
        int pos = (row < 129) ? (2 * l0 + 2 * row) : (2 * l0 - 1 + 2 * (row - 129));
        bf16x8 val;
#pragma unroll
        for (int q = 0; q < 8; ++q) val[q] = 0;
        if (pos >= 0 && pos < LIN)
            val = *(const bf16x8*)(hin + ((size_t)b * LIN + pos) * 64 + chb);
        ushort* dst = (row < 129) ? &TE[row][chb] : &TO[row - 129][chb];
        *(bf16x8*)dst = val;
    }
    __syncthreads();

    const int wv = tid >> 6, lane = tid & 63;
    const int quad = lane >> 4, l15 = lane & 15;
    const int m0 = wv * 32;

    f32x4 acc[2][4];
#pragma unroll
    for (int pt = 0; pt < 2; ++pt)
#pragma unroll
        for (int dt = 0; dt < 4; ++dt) acc[pt][dt] = (f32x4)0.f;

#pragma unroll
    for (int kk = 0; kk < 4; ++kk) {
        const ushort (*T)[72] = (kk & 1) ? TE : TO;
        const int dl = kk >> 1;
#pragma unroll
        for (int k2 = 0; k2 < 2; ++k2) {
            bf16x8 afr[4], bfr[2];
            const ushort* wb = Wg + ((((kk * 2 + k2) * 4 + quad) * 4) * 16) * 8;
#pragma unroll
            for (int dt = 0; dt < 4; ++dt)
                afr[dt] = *(const bf16x8*)(wb + ((size_t)(dt * 16 + l15)) * 8);
#pragma unroll
            for (int pt = 0; pt < 2; ++pt)
                bfr[pt] = *(const bf16x8*)&T[m0 + pt * 16 + l15 + dl][k2 * 32 + quad * 8];
#pragma unroll
            for (int pt = 0; pt < 2; ++pt)
#pragma unroll
                for (int dt = 0; dt < 4; ++dt)
                    acc[pt][dt] = __builtin_amdgcn_mfma_f32_16x16x32_bf16(
                        afr[dt], bfr[pt], acc[pt][dt], 0, 0, 0);
        }
    }

    if constexpr (STAGE == 2) {
        float vln[2][16];
#pragma unroll
        for (int pt = 0; pt < 2; ++pt) {
            float v[16];
#pragma unroll
            for (int dt = 0; dt < 4; ++dt)
#pragma unroll
                for (int r = 0; r < 4; ++r)
                    v[dt * 4 + r] = fast_tanh(acc[pt][dt][r] + cb[dt * 16 + quad * 4 + r]);
            float s = 0.f;
#pragma unroll
            for (int i = 0; i < 16; ++i) s += v[i];
            s += __shfl_xor(s, 16, 64);
            s += __shfl_xor(s, 32, 64);
            float mean = s * 0.015625f;
            float q = 0.f;
#pragma unroll
            for (int i = 0; i < 16; ++i) { float d = v[i] - mean; q = fmaf(d, d, q); }
            q += __shfl_xor(q, 16, 64);
            q += __shfl_xor(q, 32, 64);
            float rstd = rsqrtf(q * 0.015625f + LN_EPS);
#pragma unroll
            for (int dt = 0; dt < 4; ++dt)
#pragma unroll
                for (int r = 0; r < 4; ++r) {
                    int ch = dt * 16 + quad * 4 + r;
                    vln[pt][dt * 4 + r] = (v[dt * 4 + r] - mean) * rstd * lng[ch] + lnb[ch];
                }
        }
        __syncthreads();                     // tile reads done; reuse TE
        ushort* OutT = &TE[0][0];            // [128][72]
#pragma unroll
        for (int pt = 0; pt < 2; ++pt) {
            const int m = m0 + pt * 16 + l15;
#pragma unroll
            for (int dt = 0; dt < 4; ++dt) {
                bf16x4 pk;
                pk[0] = (short)f2bf(vln[pt][dt * 4 + 0]);
                pk[1] = (short)f2bf(vln[pt][dt * 4 + 1]);
                pk[2] = (short)f2bf(vln[pt][dt * 4 + 2]);
                pk[3] = (short)f2bf(vln[pt][dt * 4 + 3]);
                *(bf16x4*)&OutT[m * 72 + dt * 16 + quad * 4] = pk;
            }
        }
        __syncthreads();
        for (int idx = tid; idx < 1024; idx += 256) {
            int row = idx >> 3, chb = (idx & 7) * 8;
            *(bf16x8*)(hout + ((size_t)b * LOUT + l0 + row) * 64 + chb) =
                *(const bf16x8*)&OutT[row * 72 + chb];
        }
    } else {
#pragma unroll
        for (int pt = 0; pt < 2; ++pt) {
            const int l = l0 + m0 + pt * 16 + l15;
            float* ob = out + ((size_t)(b * 512) + l) * 64;
#pragma unroll
            for (int dt = 0; dt < 4; ++dt) {
                float4 st = make_float4(fast_tanh(acc[pt][dt][0] + cb[dt * 16 + quad * 4 + 0]),
                                        fast_tanh(acc[pt][dt][1] + cb[dt * 16 + quad * 4 + 1]),
                                        fast_tanh(acc[pt][dt][2] + cb[dt * 16 + quad * 4 + 2]),
                                        fast_tanh(acc[pt][dt][3] + cb[dt * 16 + quad * 4 + 3]));
                *(float4*)(ob + dt * 16 + quad * 4) = st;
            }
        }
    }
}

extern "C" void kernel_launch(void* const* d_in, const int* in_sizes, int n_in,
                              void* d_out, int out_size, void* d_ws, size_t ws_size,
                              hipStream_t stream) {
    (void)in_sizes; (void)n_in; (void)out_size; (void)ws_size;
    const float* x   = (const float*)d_in[0];
    const float* w3  = (const float*)d_in[1];
    const float* b3  = (const float*)d_in[2];
    const float* w5  = (const float*)d_in[3];
    const float* b5  = (const float*)d_in[4];
    const float* w7  = (const float*)d_in[5];
    const float* b7  = (const float*)d_in[6];
    const float* w9  = (const float*)d_in[7];
    const float* b9  = (const float*)d_in[8];
    const float* cw1 = (const float*)d_in[9];
    const float* cb1 = (const float*)d_in[10];
    const float* cw2 = (const float*)d_in[11];
    const float* cb2 = (const float*)d_in[12];
    const float* cw3 = (const float*)d_in[13];
    const float* cb3 = (const float*)d_in[14];
    const float* lg1 = (const float*)d_in[15];
    const float* lb1 = (const float*)d_in[16];
    const float* lg2 = (const float*)d_in[17];
    const float* lb2 = (const float*)d_in[18];
    float* out = (float*)d_out;

    // ws layout (bytes):
    char* w = (char*)d_ws;
    ushort* Wm23 = (ushort*)(w + 0);          //  65536 B (2 x 16384 bf16)
    ushort* Wm1  = (ushort*)(w + 65536);      //   4096 B (2048 bf16)
    float*  cbt  = (float*)(w + 69632);       //   1024 B
    float*  W0c  = (float*)(w + 70656);       //   1024 B
    float*  W3c  = (float*)(w + 71680);       //   1024 B
    float*  pe1c = (float*)(w + 72704);       // 524288 B (2048 x 64 fp32)
    ushort* h1   = (ushort*)(w + 596992);     // 33554432 B (128,2048,64) bf16
    ushort* h2   = (ushort*)(w + 34151424);   // 16777216 B (128,1024,64) bf16

    prep_kernel<<<128, 256, 0, stream>>>(cw1, cw2, cw3, w3, b3, w5, b5, w7, b7, w9, b9,
                                         Wm23, Wm1, cbt, W0c, W3c);
    pe1_kernel<<<32, 256, 0, stream>>>(cw1, cb1, cbt, pe1c);

    stage1_mfma<<<dim3(16, BATCH), 256, 0, stream>>>(
        x, Wm1, pe1c, W0c, W3c, lg1, lb1, h1);
    stage_mfma<2><<<dim3(8, BATCH), 256, 0, stream>>>(
        h1, Wm23, cb2, lg2, lb2, h2, nullptr);
    stage_mfma<3><<<dim3(4, BATCH), 256, 0, stream>>>(
        h2, Wm23 + 16384, cb3, nullptr, nullptr, nullptr, out);
}

// Round 7
// 191.443 us; speedup vs baseline: 1.1778x; 1.1778x over previous
//
#include <hip/hip_runtime.h>
#include <math.h>

#define BATCH 128
#define LN_EPS 1e-5f

typedef short bf16x8 __attribute__((ext_vector_type(8)));
typedef short bf16x4 __attribute__((ext_vector_type(4)));
typedef float f32x4  __attribute__((ext_vector_type(4)));

__device__ __forceinline__ ushort f2bf(float f) {
    union { float f; unsigned u; } c; c.f = f;
    unsigned r = c.u + 0x7FFF + ((c.u >> 16) & 1);   // round-nearest-even
    return (ushort)(r >> 16);
}

__device__ __forceinline__ float fast_tanh(float v) {
    float e = __expf(2.f * v);
    return 1.f - 2.f / (e + 1.f);
}

// ---------------------------------------------------------------------------
// prep (unchanged from round 6):
//  idx < 32768: Wm23 = bf16 A-frag (tap-split layout) for cw2 (s=0), cw3 (s=1)
//  idx < 64   : composite token-conv x conv1 -> Wm1 (K=16 A-frag), cbt, W0c, W3c
// ---------------------------------------------------------------------------
__global__ void prep_kernel(const float* __restrict__ cw1, const float* __restrict__ cw2,
                            const float* __restrict__ cw3,
                            const float* __restrict__ w3, const float* __restrict__ b3,
                            const float* __restrict__ w5, const float* __restrict__ b5,
                            const float* __restrict__ w7, const float* __restrict__ b7,
                            const float* __restrict__ w9, const float* __restrict__ b9,
                            ushort* __restrict__ Wm23, ushort* __restrict__ Wm1,
                            float* __restrict__ cbt, float* __restrict__ W0c,
                            float* __restrict__ W3c) {
    int idx = blockIdx.x * 256 + threadIdx.x;      // grid covers 2*16384
    if (idx < 2 * 16384) {
        int s = idx >> 14, r = idx & 16383;
        int j = r & 7, l15 = (r >> 3) & 15, dt = (r >> 7) & 3;
        int quad = (r >> 9) & 3, k2 = (r >> 11) & 1, kk = (r >> 12) & 3;
        int dout = dt * 16 + l15, din = k2 * 32 + quad * 8 + j;
        const float* cw = (s == 0) ? cw2 : cw3;
        Wm23[idx] = f2bf(cw[dout * 256 + din * 4 + kk]);
    }
    if (idx < 64) {
        const int ch = idx;
        const float* cw1row = cw1 + ch * 256;
        float weff[12], cbtv[4], w0c[4], w3c[4];
#pragma unroll
        for (int j = 0; j < 12; ++j) weff[j] = 0.f;
#pragma unroll
        for (int k = 0; k < 4; ++k) { cbtv[k] = 0.f; w0c[k] = 0.f; w3c[k] = 0.f; }
        for (int din = 0; din < 64; ++din) {
            int ki = din & 3, g = din >> 2;
            float wl[9];
#pragma unroll
            for (int j = 0; j < 9; ++j) wl[j] = 0.f;
            float bias;
            if (ki == 0)      { for (int j = 0; j < 3; ++j) wl[3 + j] = w3[g * 3 + j]; bias = b3[g]; }
            else if (ki == 1) { for (int j = 0; j < 5; ++j) wl[2 + j] = w5[g * 5 + j]; bias = b5[g]; }
            else if (ki == 2) { for (int j = 0; j < 7; ++j) wl[1 + j] = w7[g * 7 + j]; bias = b7[g]; }
            else              { for (int j = 0; j < 9; ++j) wl[j]     = w9[g * 9 + j]; bias = b9[g]; }
#pragma unroll
            for (int kk = 0; kk < 4; ++kk) {
                float c = cw1row[din * 4 + kk];
                cbtv[kk] += c * bias;
#pragma unroll
                for (int u = 0; u < 9; ++u) weff[kk + u] += c * wl[u];
            }
            float c0 = cw1row[din * 4 + 0], c3 = cw1row[din * 4 + 3];
#pragma unroll
            for (int u = 0; u < 4; ++u) { w0c[u] += c0 * wl[5 + u]; w3c[u] += c3 * wl[u]; }
        }
        int dt = ch >> 4, l15 = ch & 15;
#pragma unroll
        for (int quad = 0; quad < 4; ++quad)
#pragma unroll
            for (int j = 0; j < 8; ++j) {
                int k = quad * 8 + j;
                Wm1[((quad * 4 + dt) * 16 + l15) * 8 + j] = f2bf(k < 12 ? weff[k] : 0.f);
            }
#pragma unroll
        for (int kk = 0; kk < 4; ++kk) cbt[kk * 64 + ch] = cbtv[kk];
#pragma unroll
        for (int u = 0; u < 4; ++u) { W0c[ch * 4 + u] = w0c[u]; W3c[ch * 4 + u] = w3c[u]; }
    }
}

// ---------------------------------------------------------------------------
// pe1c[l][ch] = cb1[ch] + conv1(pe)[ch][l] + valid token-bias terms
// ---------------------------------------------------------------------------
__global__ __launch_bounds__(256, 2)
void pe1_kernel(const float* __restrict__ cw1, const float* __restrict__ cb1,
                const float* __restrict__ cbt, float* __restrict__ pe1c) {
    __shared__ float tile[64][132];
    const int tid = threadIdx.x;
    const int l0 = blockIdx.x * 64;
    const int pin0 = 2 * l0 - 1;
    for (int idx = tid; idx < 64 * 130; idx += 256) {
        int d = idx / 130, pp = idx - d * 130;
        int p = pin0 + pp;
        float v = 0.f;
        if (p >= 0 && p < 4096) {
            float dv = __expf((float)(d & ~1) * -0.14391156831212787f);  // -ln(1e4)/64
            float ang = (float)p * dv;
            v = (d & 1) ? __cosf(ang) : __sinf(ang);
        }
        tile[d][pp] = v;
    }
    __syncthreads();
    const int lane = tid & 63, wv = tid >> 6;
    const int l = l0 + lane, db = wv * 16;
    float acc[16];
#pragma unroll
    for (int j = 0; j < 16; ++j) {
        int ch = db + j;
        float a = cb1[ch] + cbt[64 + ch] + cbt[128 + ch];
        if (l > 0) a += cbt[ch];
        if (l < 2047) a += cbt[192 + ch];
        acc[j] = a;
    }
    for (int din = 0; din < 64; ++din) {
        float v0 = tile[din][2 * lane + 0], v1 = tile[din][2 * lane + 1];
        float v2 = tile[din][2 * lane + 2], v3 = tile[din][2 * lane + 3];
        const float* wb = cw1 + din * 4;
#pragma unroll
        for (int j = 0; j < 16; ++j) {
            const float* wj = wb + (db + j) * 256;
            acc[j] = fmaf(v0, wj[0], fmaf(v1, wj[1], fmaf(v2, wj[2], fmaf(v3, wj[3], acc[j]))));
        }
    }
#pragma unroll
    for (int j = 0; j < 16; ++j) pe1c[(size_t)l * 64 + db + j] = acc[j];
}

// ---------------------------------------------------------------------------
// Fully fused pipeline: block = (batch b, 64 final positions starting g0).
//   x window (bf16, LDS) -> stage1 K=16 MFMA + pe1c + tanh + LN -> TE1/TO1
//   -> stage2 tap-split K=256 MFMA + tanh + LN -> TE2/TO2
//   -> stage3 tap-split MFMA + tanh -> out fp32 (B,512,64)
// Parity tiles: TE1[r] = h1[qb+2r], TO1[r] = h1[qb+2r+1], qb = 4*g0-4.
//               TE2[r] = h2[p2b+2r], TO2[r] = h2[p2b+2r+1], p2b = 2*g0-2.
// ---------------------------------------------------------------------------
__global__ __launch_bounds__(256, 2)
void mega_kernel(const float* __restrict__ x,
                 const ushort* __restrict__ Wm1, const ushort* __restrict__ Wm23,
                 const float* __restrict__ pe1c,
                 const float* __restrict__ W0c, const float* __restrict__ W3c,
                 const float* __restrict__ lg1, const float* __restrict__ lb1,
                 const float* __restrict__ cb2, const float* __restrict__ lg2,
                 const float* __restrict__ lb2, const float* __restrict__ cb3,
                 float* __restrict__ out) {
    const int b = blockIdx.y;
    const int g0 = blockIdx.x * 64;
    const int tid = threadIdx.x;

    __shared__ __align__(16) ushort xs[640];
    __shared__ __align__(16) ushort TE1[148][72];
    __shared__ __align__(16) ushort TO1[148][72];
    __shared__ __align__(16) ushort TE2[66][72];
    __shared__ __align__(16) ushort TO2[66][72];

    // ---- x window -> bf16 LDS: xs[i] = x[8*g0 - 11 + i] ----
    for (int i = tid; i < 640; i += 256) {
        int g = 8 * g0 - 11 + i;
        float v = (g >= 0 && g < 4096) ? x[b * 4096 + g] : 0.f;
        xs[i] = f2bf(v);
    }
    __syncthreads();

    const int wv = tid >> 6, lane = tid & 63;
    const int quad = lane >> 4, l15 = lane & 15;

    // ================= stage 1: h1 positions q = (4g0-3)+m, m<264 ==========
    {
        bf16x8 afr1[4];
#pragma unroll
        for (int dt = 0; dt < 4; ++dt)
            afr1[dt] = *(const bf16x8*)&Wm1[((quad * 4 + dt) * 16 + l15) * 8];
        const int qstart = 4 * g0 - 3;
        for (int pass = wv; pass < 9; pass += 4) {
            const int mb = pass * 32;
            f32x4 a1[2][4];
#pragma unroll
            for (int pt = 0; pt < 2; ++pt) {
                const int m = mb + pt * 16 + l15;
                union { bf16x8 v; unsigned u[4]; } tmp;
                const unsigned* p = (const unsigned*)&xs[2 * m + 8 * quad];
#pragma unroll
                for (int i = 0; i < 4; ++i) tmp.u[i] = p[i];
#pragma unroll
                for (int dt = 0; dt < 4; ++dt)
                    a1[pt][dt] = __builtin_amdgcn_mfma_f32_16x16x32_bf16(
                        afr1[dt], tmp.v, (f32x4)0.f, 0, 0, 0);
            }
#pragma unroll
            for (int pt = 0; pt < 2; ++pt) {
                const int m = mb + pt * 16 + l15;
                if (m >= 264) continue;              // shfl partners share m
                const int q = qstart + m;
                ushort* dst = (m & 1) ? &TE1[(m + 1) >> 1][0] : &TO1[m >> 1][0];
                if (q >= 0 && q < 2048) {
                    float v[16];
                    const float* pb_ = pe1c + (size_t)q * 64;
#pragma unroll
                    for (int dt = 0; dt < 4; ++dt) {
                        float4 pv = *(const float4*)(pb_ + dt * 16 + quad * 4);
                        v[dt * 4 + 0] = a1[pt][dt][0] + pv.x;
                        v[dt * 4 + 1] = a1[pt][dt][1] + pv.y;
                        v[dt * 4 + 2] = a1[pt][dt][2] + pv.z;
                        v[dt * 4 + 3] = a1[pt][dt][3] + pv.w;
                    }
                    if (q == 0 || q == 2047) {       // conv1 pads emb, not x
                        const float* Wc = (q == 0) ? W0c : W3c;
                        const float* xe = x + b * 4096 + ((q == 0) ? 0 : 4092);
                        float x0 = xe[0], x1 = xe[1], x2 = xe[2], x3 = xe[3];
#pragma unroll
                        for (int dt = 0; dt < 4; ++dt)
#pragma unroll
                            for (int r = 0; r < 4; ++r) {
                                const float* wc = Wc + (dt * 16 + quad * 4 + r) * 4;
                                v[dt * 4 + r] -= wc[0] * x0 + wc[1] * x1 + wc[2] * x2 + wc[3] * x3;
                            }
                    }
#pragma unroll
                    for (int i = 0; i < 16; ++i) v[i] = fast_tanh(v[i]);
                    float s = 0.f;
#pragma unroll
                    for (int i = 0; i < 16; ++i) s += v[i];
                    s += __shfl_xor(s, 16, 64);
                    s += __shfl_xor(s, 32, 64);
                    float mean = s * 0.015625f;
                    float qq = 0.f;
#pragma unroll
                    for (int i = 0; i < 16; ++i) { float d = v[i] - mean; qq = fmaf(d, d, qq); }
                    qq += __shfl_xor(qq, 16, 64);
                    qq += __shfl_xor(qq, 32, 64);
                    float rstd = rsqrtf(qq * 0.015625f + LN_EPS);
#pragma unroll
                    for (int dt = 0; dt < 4; ++dt) {
                        bf16x4 pk;
#pragma unroll
                        for (int r = 0; r < 4; ++r) {
                            int ch = dt * 16 + quad * 4 + r;
                            pk[r] = (short)f2bf((v[dt * 4 + r] - mean) * rstd * lg1[ch] + lb1[ch]);
                        }
                        *(bf16x4*)(dst + dt * 16 + quad * 4) = pk;
                    }
                } else {
                    bf16x4 z; z[0] = 0; z[1] = 0; z[2] = 0; z[3] = 0;
#pragma unroll
                    for (int dt = 0; dt < 4; ++dt)
                        *(bf16x4*)(dst + dt * 16 + quad * 4) = z;
                }
            }
        }
    }
    __syncthreads();

    // ================= stage 2: h2 positions p = (2g0-1)+n, n<130 ==========
    for (int pass = wv; pass < 9; pass += 4) {
        const int n = pass * 16 + l15;
        f32x4 a2[4];
#pragma unroll
        for (int dt = 0; dt < 4; ++dt) a2[dt] = (f32x4)0.f;
#pragma unroll
        for (int kk = 0; kk < 4; ++kk) {
            const ushort (*T)[72] = (kk & 1) ? TE1 : TO1;
            const int row = n + ((kk + 1) >> 1);    // kk:0->n 1->n+1 2->n+1 3->n+2
#pragma unroll
            for (int k2 = 0; k2 < 2; ++k2) {
                bf16x8 bfr = *(const bf16x8*)&T[row][k2 * 32 + quad * 8];
                const ushort* wb = Wm23 + ((((kk * 2 + k2) * 4 + quad) * 4) * 16) * 8;
#pragma unroll
                for (int dt = 0; dt < 4; ++dt) {
                    bf16x8 afr = *(const bf16x8*)(wb + ((size_t)(dt * 16 + l15)) * 8);
                    a2[dt] = __builtin_amdgcn_mfma_f32_16x16x32_bf16(afr, bfr, a2[dt], 0, 0, 0);
                }
            }
        }
        if (n < 130) {
            const int p = 2 * g0 - 1 + n;
            ushort* dst = (n & 1) ? &TE2[(n + 1) >> 1][0] : &TO2[n >> 1][0];
            if (p >= 0 && p < 1024) {
                float v[16];
#pragma unroll
                for (int dt = 0; dt < 4; ++dt)
#pragma unroll
                    for (int r = 0; r < 4; ++r)
                        v[dt * 4 + r] = fast_tanh(a2[dt][r] + cb2[dt * 16 + quad * 4 + r]);
                float s = 0.f;
#pragma unroll
                for (int i = 0; i < 16; ++i) s += v[i];
                s += __shfl_xor(s, 16, 64);
                s += __shfl_xor(s, 32, 64);
                float mean = s * 0.015625f;
                float qq = 0.f;
#pragma unroll
                for (int i = 0; i < 16; ++i) { float d = v[i] - mean; qq = fmaf(d, d, qq); }
                qq += __shfl_xor(qq, 16, 64);
                qq += __shfl_xor(qq, 32, 64);
                float rstd = rsqrtf(qq * 0.015625f + LN_EPS);
#pragma unroll
                for (int dt = 0; dt < 4; ++dt) {
                    bf16x4 pk;
#pragma unroll
                    for (int r = 0; r < 4; ++r) {
                        int ch = dt * 16 + quad * 4 + r;
                        pk[r] = (short)f2bf((v[dt * 4 + r] - mean) * rstd * lg2[ch] + lb2[ch]);
                    }
                    *(bf16x4*)(dst + dt * 16 + quad * 4) = pk;
                }
            } else {
                bf16x4 z; z[0] = 0; z[1] = 0; z[2] = 0; z[3] = 0;
#pragma unroll
                for (int dt = 0; dt < 4; ++dt)
                    *(bf16x4*)(dst + dt * 16 + quad * 4) = z;
            }
        }
    }
    __syncthreads();

    // ================= stage 3: final l = g0 + m3, m3 = wv*16 + l15 ========
    {
        const int m3 = wv * 16 + l15;
        f32x4 a3[4];
#pragma unroll
        for (int dt = 0; dt < 4; ++dt) a3[dt] = (f32x4)0.f;
        const ushort* Wg3 = Wm23 + 16384;
#pragma unroll
        for (int kk = 0; kk < 4; ++kk) {
            const ushort (*T)[72] = (kk & 1) ? TE2 : TO2;
            const int row = m3 + ((kk + 1) >> 1);
#pragma unroll
            for (int k2 = 0; k2 < 2; ++k2) {
                bf16x8 bfr = *(const bf16x8*)&T[row][k2 * 32 + quad * 8];
                const ushort* wb = Wg3 + ((((kk * 2 + k2) * 4 + quad) * 4) * 16) * 8;
#pragma unroll
                for (int dt = 0; dt < 4; ++dt) {
                    bf16x8 afr = *(const bf16x8*)(wb + ((size_t)(dt * 16 + l15)) * 8);
                    a3[dt] = __builtin_amdgcn_mfma_f32_16x16x32_bf16(afr, bfr, a3[dt], 0, 0, 0);
                }
            }
        }
        const int l = g0 + m3;
        float* ob = out + ((size_t)(b * 512) + l) * 64;
#pragma unroll
        for (int dt = 0; dt < 4; ++dt) {
            float4 st = make_float4(fast_tanh(a3[dt][0] + cb3[dt * 16 + quad * 4 + 0]),
                                    fast_tanh(a3[dt][1] + cb3[dt * 16 + quad * 4 + 1]),
                                    fast_tanh(a3[dt][2] + cb3[dt * 16 + quad * 4 + 2]),
                                    fast_tanh(a3[dt][3] + cb3[dt * 16 + quad * 4 + 3]));
            *(float4*)(ob + dt * 16 + quad * 4) = st;
        }
    }
}

extern "C" void kernel_launch(void* const* d_in, const int* in_sizes, int n_in,
                              void* d_out, int out_size, void* d_ws, size_t ws_size,
                              hipStream_t stream) {
    (void)in_sizes; (void)n_in; (void)out_size; (void)ws_size;
    const float* x   = (const float*)d_in[0];
    const float* w3  = (const float*)d_in[1];
    const float* b3  = (const float*)d_in[2];
    const float* w5  = (const float*)d_in[3];
    const float* b5  = (const float*)d_in[4];
    const float* w7  = (const float*)d_in[5];
    const float* b7  = (const float*)d_in[6];
    const float* w9  = (const float*)d_in[7];
    const float* b9  = (const float*)d_in[8];
    const float* cw1 = (const float*)d_in[9];
    const float* cb1 = (const float*)d_in[10];
    const float* cw2 = (const float*)d_in[11];
    const float* cb2 = (const float*)d_in[12];
    const float* cw3 = (const float*)d_in[13];
    const float* cb3 = (const float*)d_in[14];
    const float* lg1 = (const float*)d_in[15];
    const float* lb1 = (const float*)d_in[16];
    const float* lg2 = (const float*)d_in[17];
    const float* lb2 = (const float*)d_in[18];
    float* out = (float*)d_out;

    // ws layout (bytes) — ~590 KB total, no HBM intermediates:
    char* w = (char*)d_ws;
    ushort* Wm23 = (ushort*)(w + 0);          //  65536 B (2 x 16384 bf16)
    ushort* Wm1  = (ushort*)(w + 65536);      //   4096 B (2048 bf16)
    float*  cbt  = (float*)(w + 69632);       //   1024 B
    float*  W0c  = (float*)(w + 70656);       //   1024 B
    float*  W3c  = (float*)(w + 71680);       //   1024 B
    float*  pe1c = (float*)(w + 72704);       // 524288 B (2048 x 64 fp32)

    prep_kernel<<<128, 256, 0, stream>>>(cw1, cw2, cw3, w3, b3, w5, b5, w7, b7, w9, b9,
                                         Wm23, Wm1, cbt, W0c, W3c);
    pe1_kernel<<<32, 256, 0, stream>>>(cw1, cb1, cbt, pe1c);
    mega_kernel<<<dim3(8, BATCH), 256, 0, stream>>>(
        x, Wm1, Wm23, pe1c, W0c, W3c, lg1, lb1, cb2, lg2, lb2, cb3, out);
}